// Round 7
// baseline (493.362 us; speedup 1.0000x reference)
//
#include <hip/hip_runtime.h>

// LSTM T=512, B=4096, I=10, H=20, fp32.
// One lane = one (batch, unit, gate). Block = 320 = 4 batch x 20 units x 4 gates.
// Round-4 changes vs round-3 (which ran 328us at VGPR=32 -- compiler sank the
// weight loads into the loop instead of keeping them resident):
//  1. Weights PINNED in VGPRs via empty asm "+v" (opaque producer -> no remat).
//  2. Gate broadcast via DPP quad_perm (VALU) instead of ds_swizzle (LDS pipe).
//  3. x-prefetch spread across lanes 0..7 of EACH wave (round 3 put all 40
//     loads on wave 0, making it the straggler at every barrier).

constexpr int kT = 512, kB = 4096, kI = 10, kH = 20;
constexpr int BPB = 4;                  // batch elements per block
constexpr int THREADS = BPB * kH * 4;   // 320 = 5 waves

__global__ __launch_bounds__(THREADS, 5) void lstm_gsplit2(
    const float* __restrict__ x, const float* __restrict__ hx,
    const float* __restrict__ cx, const float* __restrict__ W_ih,
    const float* __restrict__ W_hh, const float* __restrict__ b_ih,
    const float* __restrict__ b_hh, float* __restrict__ out)
{
    __shared__ float h_s[2][BPB][kH];    // 640 B
    __shared__ float x_s[2][BPB][12];    // rows padded to 12 floats (16B-aligned)

    const int tid = threadIdx.x;
    const int b_loc = tid / 80;          // 0..3
    const int r = tid % 80;
    const int u = r >> 2;                // 0..19
    const int k = r & 3;                 // 0:i 1:f 2:g 3:o (PyTorch order)
    const int b0 = blockIdx.x * BPB;
    const int b = b0 + b_loc;
    const int row = k * kH + u;

    // ---- per-lane weights -> registers, then PIN so they stay there ----
    float Wih[kI], Whh[kH];
    #pragma unroll
    for (int i = 0; i < kI; ++i) Wih[i] = W_ih[row * kI + i];
    #pragma unroll
    for (int j = 0; j < kH; ++j) Whh[j] = W_hh[row * kH + j];
    float bias = b_ih[row] + b_hh[row];
    #pragma unroll
    for (int i = 0; i < kI; ++i) asm volatile("" : "+v"(Wih[i]));
    #pragma unroll
    for (int j = 0; j < kH; ++j) asm volatile("" : "+v"(Whh[j]));
    asm volatile("" : "+v"(bias));

    // unified activation: act = fma(rcp(1+exp2(c0*a)), c1, c2)
    // sigmoid: c0=-log2(e), c1=1, c2=0 ; tanh: c0=-2log2(e), c1=2, c2=-1
    const float c0 = (k == 2) ? -2.885390082f : -1.442695041f;
    const float c1 = (k == 2) ? 2.0f : 1.0f;
    const float c2 = (k == 2) ? -1.0f : 0.0f;

    float c = cx[(size_t)b * kH + u];

    // x-prefetch assignment: lanes 0..7 of each wave -> slots 0..39
    const int lane = tid & 63, wv = tid >> 6;
    const int slot = wv * 8 + lane;          // meaningful only when lane<8
    const bool pf = (lane < 8);
    const int pb = slot / kI, pi = slot - pb * kI;
    const size_t xstride = (size_t)kB * kI;

    // ---- initial staging (t=0) ----
    if (pf) x_s[0][pb][pi] = x[(size_t)b0 * kI + slot];
    if (tid < BPB * kH) h_s[0][tid / kH][tid - (tid / kH) * kH] = hx[(size_t)b0 * kH + tid];
    __syncthreads();

    const float* xpf_p = x + xstride + (size_t)b0 * kI + slot;   // x[t=1]
    float* outp = out + (size_t)b * kH + u;

    for (int t = 0; t < kT; ++t) {
        const int rb = t & 1, wb = rb ^ 1;

        // prefetch x[t+1] (uniform t-guard; latency hides under the FMAs)
        float xp = 0.0f;
        if ((t + 1 < kT) && pf) xp = *xpf_p;

        // gate pre-activation: 30 FMAs; LDS reads are same-address broadcasts
        float a = bias;
        #pragma unroll
        for (int i = 0; i < kI; ++i) a = fmaf(Wih[i], x_s[rb][b_loc][i], a);
        #pragma unroll
        for (int j = 0; j < kH; ++j) a = fmaf(Whh[j], h_s[rb][b_loc][j], a);

        float e = __builtin_amdgcn_exp2f(c0 * a);
        float act = fmaf(__builtin_amdgcn_rcpf(1.0f + e), c1, c2);

        // broadcast gates i,f,g within each 4-lane group: DPP quad_perm (VALU)
        const int ai = __float_as_int(act);
        const float iv = __int_as_float(__builtin_amdgcn_update_dpp(0, ai, 0x00, 0xF, 0xF, true));
        const float fv = __int_as_float(__builtin_amdgcn_update_dpp(0, ai, 0x55, 0xF, 0xF, true));
        const float gv = __int_as_float(__builtin_amdgcn_update_dpp(0, ai, 0xAA, 0xF, 0xF, true));

        c = fmaf(fv, c, iv * gv);                    // redundant in all 4 lanes
        float e2 = __builtin_amdgcn_exp2f(-2.885390082f * c);
        float th = fmaf(__builtin_amdgcn_rcpf(1.0f + e2), 2.0f, -1.0f);
        float hn = act * th;                         // valid on k==3 (act==o)

        if (k == 3) {
            h_s[wb][b_loc][u] = hn;
            *outp = hn;
        }
        if (pf) x_s[wb][pb][pi] = xp;

        outp  += (size_t)kB * kH;
        xpf_p += xstride;
        __syncthreads();                             // writes -> next step's reads
    }
}

extern "C" void kernel_launch(void* const* d_in, const int* in_sizes, int n_in,
                              void* d_out, int out_size, void* d_ws, size_t ws_size,
                              hipStream_t stream) {
    const float* x    = (const float*)d_in[0];
    const float* hx   = (const float*)d_in[1];
    const float* cx   = (const float*)d_in[2];
    const float* W_ih = (const float*)d_in[3];
    const float* W_hh = (const float*)d_in[4];
    const float* b_ih = (const float*)d_in[5];
    const float* b_hh = (const float*)d_in[6];
    float* out = (float*)d_out;

    lstm_gsplit2<<<kB / BPB, THREADS, 0, stream>>>(x, hx, cx, W_ih, W_hh, b_ih, b_hh, out);
}